// Round 2
// baseline (3310.093 us; speedup 1.0000x reference)
//
#include <hip/hip_runtime.h>

#define N_USERS 100000
#define N_ITEMS 50000
#define N_TOTAL 150000
#define F 64
#define NNZ 4800000
#define BATCH 16384

// -------------------------------------------------------------------------
// SpMM push-scatter: one WAVE per edge, lane f handles factor f.
//   dst[row[e]][f] += vals[e] * src[col[e]][f]
// Coalesced 256B gather + coalesced 256B atomic scatter per edge.
// unsafeAtomicAdd -> global_atomic_add_f32 (HW fp32 atomic, no CAS loop).
// -------------------------------------------------------------------------
__global__ __launch_bounds__(256) void spmm_scatter(
    const float* __restrict__ vals,
    const int*   __restrict__ row,
    const int*   __restrict__ col,
    const float* __restrict__ src,
    float*       __restrict__ dst)
{
    const int e = blockIdx.x * 4 + (threadIdx.x >> 6);   // 4 waves/block, 1 edge/wave
    const int f = threadIdx.x & 63;
    if (e >= NNZ) return;
    const int   r = row[e];
    const int   c = col[e];
    const float v = vals[e];
    const float g = src[(size_t)c * F + f] * v;
    unsafeAtomicAdd(&dst[(size_t)r * F + f], g);
}

// -------------------------------------------------------------------------
// acc += src (float4-vectorized), optionally clear another buffer to zero
// for the next scatter. Grid-stride.
// -------------------------------------------------------------------------
__global__ __launch_bounds__(256) void add_and_clear(
    float* __restrict__ acc,
    const float* __restrict__ src,
    float* __restrict__ clearbuf,          // may be null
    int n4)                                 // count of float4
{
    const int stride = gridDim.x * blockDim.x;
    for (int i = blockIdx.x * blockDim.x + threadIdx.x; i < n4; i += stride) {
        float4 a = ((const float4*)acc)[i];
        float4 s = ((const float4*)src)[i];
        a.x += s.x; a.y += s.y; a.z += s.z; a.w += s.w;
        ((float4*)acc)[i] = a;
        if (clearbuf) ((float4*)clearbuf)[i] = make_float4(0.f, 0.f, 0.f, 0.f);
    }
}

// -------------------------------------------------------------------------
// Final: out[b] = dot(acc[users[b]], acc[N_USERS+items[b]]) / 16
// (each side divided by LAYERS+1 = 4). One wave per batch element.
// -------------------------------------------------------------------------
__global__ __launch_bounds__(256) void batch_dot(
    const float* __restrict__ acc,
    const int*   __restrict__ users, const int* __restrict__ items,
    float*       __restrict__ out)
{
    const int b = blockIdx.x * 4 + (threadIdx.x >> 6);
    const int f = threadIdx.x & 63;
    if (b >= BATCH) return;

    const float su = acc[(size_t)users[b] * F + f];
    const float si = acc[((size_t)(N_USERS + items[b])) * F + f];
    float p = su * si;

    #pragma unroll
    for (int off = 32; off > 0; off >>= 1)
        p += __shfl_down(p, off, 64);

    if (f == 0) out[b] = p * (1.0f / 16.0f);
}

extern "C" void kernel_launch(void* const* d_in, const int* in_sizes, int n_in,
                              void* d_out, int out_size, void* d_ws, size_t ws_size,
                              hipStream_t stream)
{
    const float* user_w   = (const float*)d_in[0];
    const float* item_w   = (const float*)d_in[1];
    const float* adj_vals = (const float*)d_in[2];
    const int*   adj_row  = (const int*)d_in[3];
    const int*   adj_col  = (const int*)d_in[4];
    const int*   users    = (const int*)d_in[5];
    const int*   items    = (const int*)d_in[6];
    float*       out      = (float*)d_out;

    const size_t embN = (size_t)N_TOTAL * F;         // 9.6M floats = 38.4 MB
    const size_t need = 3 * embN * sizeof(float);    // 115.2 MB

    if (ws_size < need) {
        // Defensive: not enough scratch — fail visibly (wrong output),
        // never write out of bounds.
        hipMemsetAsync(d_out, 0, (size_t)out_size * sizeof(float), stream);
        return;
    }

    float* acc  = (float*)d_ws;
    float* bufA = acc  + embN;
    float* bufB = bufA + embN;
    const int n4 = (int)(embN / 4);                  // 2.4M float4

    // emb0 = concat(user_w, item_w) into bufA AND acc
    const size_t ubytes = (size_t)N_USERS * F * sizeof(float);
    const size_t ibytes = (size_t)N_ITEMS * F * sizeof(float);
    hipMemcpyAsync(bufA, user_w, ubytes, hipMemcpyDeviceToDevice, stream);
    hipMemcpyAsync(bufA + (size_t)N_USERS * F, item_w, ibytes, hipMemcpyDeviceToDevice, stream);
    hipMemcpyAsync(acc,  user_w, ubytes, hipMemcpyDeviceToDevice, stream);
    hipMemcpyAsync(acc + (size_t)N_USERS * F, item_w, ibytes, hipMemcpyDeviceToDevice, stream);
    hipMemsetAsync(bufB, 0, embN * sizeof(float), stream);

    const int scatter_blocks = NNZ / 4;              // 4 edges (waves) / 256-thr block
    const int ac_blocks = 2048;

    // layer 1: bufB = spmm(bufA); acc += bufB; bufA = 0
    spmm_scatter<<<scatter_blocks, 256, 0, stream>>>(adj_vals, adj_row, adj_col, bufA, bufB);
    add_and_clear<<<ac_blocks, 256, 0, stream>>>(acc, bufB, bufA, n4);
    // layer 2: bufA = spmm(bufB); acc += bufA; bufB = 0
    spmm_scatter<<<scatter_blocks, 256, 0, stream>>>(adj_vals, adj_row, adj_col, bufB, bufA);
    add_and_clear<<<ac_blocks, 256, 0, stream>>>(acc, bufA, bufB, n4);
    // layer 3: bufB = spmm(bufA); acc += bufB
    spmm_scatter<<<scatter_blocks, 256, 0, stream>>>(adj_vals, adj_row, adj_col, bufA, bufB);
    add_and_clear<<<ac_blocks, 256, 0, stream>>>(acc, bufB, nullptr, n4);

    batch_dot<<<BATCH / 4, 256, 0, stream>>>(acc, users, items, out);
}

// Round 6
// 1904.897 us; speedup vs baseline: 1.7377x; 1.7377x over previous
//
#include <hip/hip_runtime.h>

#define N_USERS 100000
#define N_ITEMS 50000
#define N_TOTAL 150000
#define F 64
#define NNZ 4800000
#define BATCH 16384
#define SCAN_THREADS 1024

// ---------------- CSR build ----------------

__global__ __launch_bounds__(256) void hist_kernel(
    const int* __restrict__ row, int* __restrict__ deg)
{
    int i = blockIdx.x * 256 + threadIdx.x;
    const int stride = gridDim.x * 256;
    for (; i < NNZ; i += stride) atomicAdd(&deg[row[i]], 1);
}

// Exclusive scan of deg[N_TOTAL] -> row_ptr[N_TOTAL+1], also copy into cursor.
// Single block of 1024 threads; each thread serially owns a 147-element chunk.
__global__ __launch_bounds__(SCAN_THREADS) void scan_kernel(
    const int* __restrict__ deg, int* __restrict__ row_ptr, int* __restrict__ cursor)
{
    __shared__ int part[SCAN_THREADS];
    const int t  = threadIdx.x;
    const int CH = (N_TOTAL + SCAN_THREADS - 1) / SCAN_THREADS;  // 147
    const int lo = t * CH;
    const int hi = min(lo + CH, N_TOTAL);
    int s = 0;
    for (int i = lo; i < hi; ++i) s += deg[i];
    part[t] = s;
    __syncthreads();
    // Hillis-Steele inclusive scan (read old, sync, write, sync)
    for (int off = 1; off < SCAN_THREADS; off <<= 1) {
        int v = (t >= off) ? part[t - off] : 0;
        __syncthreads();
        part[t] += v;
        __syncthreads();
    }
    int excl = part[t] - s;  // exclusive prefix for this chunk
    for (int i = lo; i < hi; ++i) {
        row_ptr[i] = excl;
        cursor[i]  = excl;
        excl += deg[i];
    }
    if (t == SCAN_THREADS - 1) row_ptr[N_TOTAL] = NNZ;
}

// Bucket edges into CSR order: csr[p] = {col, bits(val)}
__global__ __launch_bounds__(256) void fill_kernel(
    const int* __restrict__ row, const int* __restrict__ col,
    const float* __restrict__ vals, int* __restrict__ cursor,
    int2* __restrict__ csr)
{
    int i = blockIdx.x * 256 + threadIdx.x;
    const int stride = gridDim.x * 256;
    for (; i < NNZ; i += stride) {
        const int r = row[i];
        const int p = atomicAdd(&cursor[r], 1);
        csr[p] = make_int2(col[i], __float_as_int(vals[i]));
    }
}

// Assign compact indices to the (deduped) queried rows.
__global__ __launch_bounds__(256) void assign_kernel(
    const int* __restrict__ users, const int* __restrict__ items,
    int* __restrict__ remap, int* __restrict__ list, int* __restrict__ counter)
{
    const int i = blockIdx.x * 256 + threadIdx.x;
    if (i >= 2 * BATCH) return;
    const int r = (i < BATCH) ? users[i] : (N_USERS + items[i - BATCH]);
    if (atomicCAS(&remap[r], -1, -2) == -1) {
        const int idx = atomicAdd(counter, 1);
        list[idx] = r;
        remap[r]  = idx;   // nobody reads remap until later kernels
    }
}

// ---------------- pull-style SpMM ----------------

// One wave computes one row: p[lane] = sum_e val_e * src[col_e][lane].
// Edges loaded cooperatively (64 at a time, coalesced) then shfl-broadcast.
__device__ __forceinline__ float spmm_row(
    const int2* __restrict__ csr, int start, int end,
    const float* __restrict__ src, int lane)
{
    float p = 0.f;
    int base = start;
    // full 64-edge batches: compile-time trip count -> clean unroll
    for (; base + 64 <= end; base += 64) {
        const int2 cv = csr[base + lane];
        #pragma unroll
        for (int j = 0; j < 64; ++j) {
            const int   c = __builtin_amdgcn_readfirstlane(__shfl(cv.x, j, 64));
            const float v = __int_as_float(__shfl(cv.y, j, 64));
            p += v * src[(size_t)c * F + lane];
        }
    }
    // remainder
    if (base < end) {
        const int rem = end - base;
        int2 cv = make_int2(0, 0);
        if (lane < rem) cv = csr[base + lane];
        for (int j = 0; j < rem; ++j) {
            const int   c = __builtin_amdgcn_readfirstlane(__shfl(cv.x, j, 64));
            const float v = __int_as_float(__shfl(cv.y, j, 64));
            p += v * src[(size_t)c * F + lane];
        }
    }
    return p;
}

__global__ __launch_bounds__(256) void spmm_layer(
    const int* __restrict__ row_ptr, const int2* __restrict__ csr,
    const float* __restrict__ src, float* __restrict__ dst)
{
    const int r    = blockIdx.x * 4 + (threadIdx.x >> 6);
    const int lane = threadIdx.x & 63;
    if (r >= N_TOTAL) return;
    const float p = spmm_row(csr, row_ptr[r], row_ptr[r + 1], src, lane);
    dst[(size_t)r * F + lane] = p;
}

// Layer 2 + fused epilogue: accC[remap[r]] = e0[r] + e1[r] for queried rows.
__global__ __launch_bounds__(256) void spmm_layer2(
    const int* __restrict__ row_ptr, const int2* __restrict__ csr,
    const float* __restrict__ src /*e1*/, float* __restrict__ dst /*e2*/,
    const float* __restrict__ uw, const float* __restrict__ iw,
    const int* __restrict__ remap, float* __restrict__ accC)
{
    const int r    = blockIdx.x * 4 + (threadIdx.x >> 6);
    const int lane = threadIdx.x & 63;
    if (r >= N_TOTAL) return;
    const float p = spmm_row(csr, row_ptr[r], row_ptr[r + 1], src, lane);
    dst[(size_t)r * F + lane] = p;
    const int idx = remap[r];
    if (idx >= 0) {
        const float e0 = (r < N_USERS) ? uw[(size_t)r * F + lane]
                                       : iw[(size_t)(r - N_USERS) * F + lane];
        accC[(size_t)idx * F + lane] = e0 + src[(size_t)r * F + lane];
    }
}

// Layer 3: ONLY queried rows. accC[idx] += e2[r] + spmm_row(e2).
__global__ __launch_bounds__(256) void spmm_layer3(
    const int* __restrict__ row_ptr, const int2* __restrict__ csr,
    const float* __restrict__ src /*e2*/, const int* __restrict__ list,
    const int* __restrict__ counter, float* __restrict__ accC)
{
    const int idx  = blockIdx.x * 4 + (threadIdx.x >> 6);
    const int lane = threadIdx.x & 63;
    if (idx >= *counter) return;
    const int r = list[idx];
    const float p = spmm_row(csr, row_ptr[r], row_ptr[r + 1], src, lane);
    accC[(size_t)idx * F + lane] += src[(size_t)r * F + lane] + p;
}

// out[b] = dot(acc[u], acc[i]) / 16   (each side's /4 folded together)
__global__ __launch_bounds__(256) void batch_dot(
    const float* __restrict__ accC, const int* __restrict__ remap,
    const int* __restrict__ users, const int* __restrict__ items,
    float* __restrict__ out)
{
    const int b    = blockIdx.x * 4 + (threadIdx.x >> 6);
    const int lane = threadIdx.x & 63;
    if (b >= BATCH) return;
    const int iu = remap[users[b]];
    const int ii = remap[N_USERS + items[b]];
    float p = accC[(size_t)iu * F + lane] * accC[(size_t)ii * F + lane];
    #pragma unroll
    for (int off = 32; off > 0; off >>= 1) p += __shfl_down(p, off, 64);
    if (lane == 0) out[b] = p * (1.0f / 16.0f);
}

// ---------------- launch ----------------

extern "C" void kernel_launch(void* const* d_in, const int* in_sizes, int n_in,
                              void* d_out, int out_size, void* d_ws, size_t ws_size,
                              hipStream_t stream)
{
    const float* user_w   = (const float*)d_in[0];
    const float* item_w   = (const float*)d_in[1];
    const float* adj_vals = (const float*)d_in[2];
    const int*   adj_row  = (const int*)d_in[3];
    const int*   adj_col  = (const int*)d_in[4];
    const int*   users    = (const int*)d_in[5];
    const int*   items    = (const int*)d_in[6];
    float*       out      = (float*)d_out;

    const size_t embB  = (size_t)N_TOTAL * F * sizeof(float);   // 38.4 MB
    const size_t csrB  = (size_t)NNZ * sizeof(int2);            // 38.4 MB
    const size_t rpB   = ((size_t)(N_TOTAL + 1) * 4 + 255) & ~(size_t)255;
    const size_t curB  = ((size_t)N_TOTAL * 4 + 255) & ~(size_t)255;
    const size_t rmB   = curB;
    const size_t listB = (size_t)2 * BATCH * 4;                 // 128 KB
    const size_t cntB  = 256;
    const size_t accB  = (size_t)2 * BATCH * F * sizeof(float); // 8 MB

    const size_t need = 2 * embB + csrB + rpB + curB + rmB + listB + cntB + accB;
    if (ws_size < need) {   // defensive: fail visibly, never write OOB
        hipMemsetAsync(d_out, 0, (size_t)out_size * sizeof(float), stream);
        return;
    }

    char* w = (char*)d_ws;
    float* eA      = (float*)w;  w += embB;   // e0 then e2
    float* eB      = (float*)w;  w += embB;   // e1
    int2*  csr     = (int2*)w;   w += csrB;
    int*   row_ptr = (int*)w;    w += rpB;
    int*   cursor  = (int*)w;    w += curB;   // deg, then fill cursor
    int*   remap   = (int*)w;    w += rmB;
    int*   list    = (int*)w;    w += listB;
    int*   counter = (int*)w;    w += cntB;
    float* accC    = (float*)w;  w += accB;

    // init (ws is poisoned 0xAA before every call)
    hipMemsetAsync(cursor, 0, curB, stream);
    hipMemsetAsync(remap, 0xFF, rmB, stream);          // -1
    hipMemsetAsync(counter, 0, 4, stream);

    // CSR build
    hist_kernel<<<2048, 256, 0, stream>>>(adj_row, cursor);
    scan_kernel<<<1, SCAN_THREADS, 0, stream>>>(cursor, row_ptr, cursor);
    // scan reads deg from `cursor` and rewrites it as prefix — same buffer is
    // safe: each thread reads deg[i] before overwriting (chunk-local serial).
    fill_kernel<<<2048, 256, 0, stream>>>(adj_row, adj_col, adj_vals, cursor, csr);
    assign_kernel<<<(2 * BATCH + 255) / 256, 256, 0, stream>>>(users, items, remap, list, counter);

    // e0 = concat(user_w, item_w)
    hipMemcpyAsync(eA, user_w, (size_t)N_USERS * F * sizeof(float),
                   hipMemcpyDeviceToDevice, stream);
    hipMemcpyAsync(eA + (size_t)N_USERS * F, item_w, (size_t)N_ITEMS * F * sizeof(float),
                   hipMemcpyDeviceToDevice, stream);

    const int rows_blocks = (N_TOTAL + 3) / 4;   // 4 rows (waves) per block
    // L1: e1 = A @ e0
    spmm_layer <<<rows_blocks, 256, 0, stream>>>(row_ptr, csr, eA, eB);
    // L2: e2 = A @ e1 (into eA), fused accC = e0 + e1 at queried rows
    spmm_layer2<<<rows_blocks, 256, 0, stream>>>(row_ptr, csr, eB, eA,
                                                 user_w, item_w, remap, accC);
    // L3: queried rows only; accC += e2 + A @ e2
    spmm_layer3<<<(2 * BATCH + 3) / 4, 256, 0, stream>>>(row_ptr, csr, eA, list, counter, accC);

    batch_dot<<<(BATCH + 3) / 4, 256, 0, stream>>>(accC, remap, users, items, out);
}

// Round 7
// 1262.097 us; speedup vs baseline: 2.6227x; 1.5093x over previous
//
#include <hip/hip_runtime.h>

#define N_USERS 100000
#define N_ITEMS 50000
#define N_TOTAL 150000
#define F 64
#define NNZ 4800000
#define BATCH 16384
#define SCAN_THREADS 1024

// ---------------- CSR build ----------------

__global__ __launch_bounds__(256) void hist_kernel(
    const int* __restrict__ row, int* __restrict__ deg)
{
    int i = blockIdx.x * 256 + threadIdx.x;
    const int stride = gridDim.x * 256;
    for (; i < NNZ; i += stride) atomicAdd(&deg[row[i]], 1);
}

// Exclusive scan of deg[N_TOTAL] -> row_ptr[N_TOTAL+1], also copy into cursor.
// Single block of 1024 threads; each thread serially owns a 147-element chunk.
__global__ __launch_bounds__(SCAN_THREADS) void scan_kernel(
    const int* __restrict__ deg, int* __restrict__ row_ptr, int* __restrict__ cursor)
{
    __shared__ int part[SCAN_THREADS];
    const int t  = threadIdx.x;
    const int CH = (N_TOTAL + SCAN_THREADS - 1) / SCAN_THREADS;  // 147
    const int lo = t * CH;
    const int hi = min(lo + CH, N_TOTAL);
    int s = 0;
    for (int i = lo; i < hi; ++i) s += deg[i];
    part[t] = s;
    __syncthreads();
    // Hillis-Steele inclusive scan (read old, sync, write, sync)
    for (int off = 1; off < SCAN_THREADS; off <<= 1) {
        int v = (t >= off) ? part[t - off] : 0;
        __syncthreads();
        part[t] += v;
        __syncthreads();
    }
    int excl = part[t] - s;  // exclusive prefix for this chunk
    for (int i = lo; i < hi; ++i) {
        row_ptr[i] = excl;
        cursor[i]  = excl;
        excl += deg[i];
    }
    if (t == SCAN_THREADS - 1) row_ptr[N_TOTAL] = NNZ;
}

// Bucket edges into CSR order: csr[p] = {col, bits(val)}
__global__ __launch_bounds__(256) void fill_kernel(
    const int* __restrict__ row, const int* __restrict__ col,
    const float* __restrict__ vals, int* __restrict__ cursor,
    int2* __restrict__ csr)
{
    int i = blockIdx.x * 256 + threadIdx.x;
    const int stride = gridDim.x * 256;
    for (; i < NNZ; i += stride) {
        const int r = row[i];
        const int p = atomicAdd(&cursor[r], 1);
        csr[p] = make_int2(col[i], __float_as_int(vals[i]));
    }
}

// Assign compact indices to the (deduped) queried rows.
__global__ __launch_bounds__(256) void assign_kernel(
    const int* __restrict__ users, const int* __restrict__ items,
    int* __restrict__ remap, int* __restrict__ list, int* __restrict__ counter)
{
    const int i = blockIdx.x * 256 + threadIdx.x;
    if (i >= 2 * BATCH) return;
    const int r = (i < BATCH) ? users[i] : (N_USERS + items[i - BATCH]);
    if (atomicCAS(&remap[r], -1, -2) == -1) {
        const int idx = atomicAdd(counter, 1);
        list[idx] = r;
        remap[r]  = idx;   // nobody reads remap until later kernels
    }
}

// ---------------- pull-style SpMM ----------------

// One wave computes one row: p[lane] = sum_e val_e * src[col_e][lane].
// Edge list loaded wave-wide (zero-padded), then broadcast via readlane
// (SGPR path, NO ds_bpermute) in statically-unrolled chunks of 16 so the
// 16 gathers issue back-to-back and pipeline across chunks.
// Pad lanes have v=0 -> fma contributes 0; c=0 gather hits a hot line.
__device__ __forceinline__ float spmm_row(
    const int2* __restrict__ csr, int start, int end,
    const float* __restrict__ src, int lane)
{
    float p = 0.f;
    for (int base = start; base < end; base += 64) {
        int2 cv = make_int2(0, 0);
        if (base + lane < end) cv = csr[base + lane];
        const int cnt = min(64, end - base);
        for (int ch = 0; ch < cnt; ch += 16) {
            #pragma unroll
            for (int j = 0; j < 16; ++j) {
                const int   c = __builtin_amdgcn_readlane(cv.x, ch + j);
                const float v = __int_as_float(__builtin_amdgcn_readlane(cv.y, ch + j));
                p = fmaf(v, src[(size_t)c * F + lane], p);
            }
        }
    }
    return p;
}

__global__ __launch_bounds__(256) void spmm_layer(
    const int* __restrict__ row_ptr, const int2* __restrict__ csr,
    const float* __restrict__ src, float* __restrict__ dst)
{
    const int r    = blockIdx.x * 4 + (threadIdx.x >> 6);
    const int lane = threadIdx.x & 63;
    if (r >= N_TOTAL) return;
    const float p = spmm_row(csr, row_ptr[r], row_ptr[r + 1], src, lane);
    dst[(size_t)r * F + lane] = p;
}

// Layer 2 + fused epilogue: accC[remap[r]] = e0[r] + e1[r] for queried rows.
__global__ __launch_bounds__(256) void spmm_layer2(
    const int* __restrict__ row_ptr, const int2* __restrict__ csr,
    const float* __restrict__ src /*e1*/, float* __restrict__ dst /*e2*/,
    const float* __restrict__ uw, const float* __restrict__ iw,
    const int* __restrict__ remap, float* __restrict__ accC)
{
    const int r    = blockIdx.x * 4 + (threadIdx.x >> 6);
    const int lane = threadIdx.x & 63;
    if (r >= N_TOTAL) return;
    const float p = spmm_row(csr, row_ptr[r], row_ptr[r + 1], src, lane);
    dst[(size_t)r * F + lane] = p;
    const int idx = remap[r];
    if (idx >= 0) {
        const float e0 = (r < N_USERS) ? uw[(size_t)r * F + lane]
                                       : iw[(size_t)(r - N_USERS) * F + lane];
        accC[(size_t)idx * F + lane] = e0 + src[(size_t)r * F + lane];
    }
}

// Layer 3: ONLY queried rows. accC[idx] += e2[r] + spmm_row(e2).
__global__ __launch_bounds__(256) void spmm_layer3(
    const int* __restrict__ row_ptr, const int2* __restrict__ csr,
    const float* __restrict__ src /*e2*/, const int* __restrict__ list,
    const int* __restrict__ counter, float* __restrict__ accC)
{
    const int idx  = blockIdx.x * 4 + (threadIdx.x >> 6);
    const int lane = threadIdx.x & 63;
    if (idx >= *counter) return;
    const int r = list[idx];
    const float p = spmm_row(csr, row_ptr[r], row_ptr[r + 1], src, lane);
    accC[(size_t)idx * F + lane] += src[(size_t)r * F + lane] + p;
}

// out[b] = dot(acc[u], acc[i]) / 16   (each side's /4 folded together)
__global__ __launch_bounds__(256) void batch_dot(
    const float* __restrict__ accC, const int* __restrict__ remap,
    const int* __restrict__ users, const int* __restrict__ items,
    float* __restrict__ out)
{
    const int b    = blockIdx.x * 4 + (threadIdx.x >> 6);
    const int lane = threadIdx.x & 63;
    if (b >= BATCH) return;
    const int iu = remap[users[b]];
    const int ii = remap[N_USERS + items[b]];
    float p = accC[(size_t)iu * F + lane] * accC[(size_t)ii * F + lane];
    #pragma unroll
    for (int off = 32; off > 0; off >>= 1) p += __shfl_down(p, off, 64);
    if (lane == 0) out[b] = p * (1.0f / 16.0f);
}

// ---------------- launch ----------------

extern "C" void kernel_launch(void* const* d_in, const int* in_sizes, int n_in,
                              void* d_out, int out_size, void* d_ws, size_t ws_size,
                              hipStream_t stream)
{
    const float* user_w   = (const float*)d_in[0];
    const float* item_w   = (const float*)d_in[1];
    const float* adj_vals = (const float*)d_in[2];
    const int*   adj_row  = (const int*)d_in[3];
    const int*   adj_col  = (const int*)d_in[4];
    const int*   users    = (const int*)d_in[5];
    const int*   items    = (const int*)d_in[6];
    float*       out      = (float*)d_out;

    const size_t embB  = (size_t)N_TOTAL * F * sizeof(float);   // 38.4 MB
    const size_t csrB  = (size_t)NNZ * sizeof(int2);            // 38.4 MB
    const size_t rpB   = ((size_t)(N_TOTAL + 1) * 4 + 255) & ~(size_t)255;
    const size_t curB  = ((size_t)N_TOTAL * 4 + 255) & ~(size_t)255;
    const size_t rmB   = curB;
    const size_t listB = (size_t)2 * BATCH * 4;                 // 128 KB
    const size_t cntB  = 256;
    const size_t accB  = (size_t)2 * BATCH * F * sizeof(float); // 8 MB

    const size_t need = 2 * embB + csrB + rpB + curB + rmB + listB + cntB + accB;
    if (ws_size < need) {   // defensive: fail visibly, never write OOB
        hipMemsetAsync(d_out, 0, (size_t)out_size * sizeof(float), stream);
        return;
    }

    char* w = (char*)d_ws;
    float* eA      = (float*)w;  w += embB;   // e0 then e2
    float* eB      = (float*)w;  w += embB;   // e1
    int2*  csr     = (int2*)w;   w += csrB;
    int*   row_ptr = (int*)w;    w += rpB;
    int*   cursor  = (int*)w;    w += curB;   // deg, then fill cursor
    int*   remap   = (int*)w;    w += rmB;
    int*   list    = (int*)w;    w += listB;
    int*   counter = (int*)w;    w += cntB;
    float* accC    = (float*)w;  w += accB;

    // init (ws is poisoned 0xAA before every call)
    hipMemsetAsync(cursor, 0, curB, stream);
    hipMemsetAsync(remap, 0xFF, rmB, stream);          // -1
    hipMemsetAsync(counter, 0, 4, stream);

    // CSR build
    hist_kernel<<<2048, 256, 0, stream>>>(adj_row, cursor);
    scan_kernel<<<1, SCAN_THREADS, 0, stream>>>(cursor, row_ptr, cursor);
    // scan reads deg from `cursor` and rewrites it as prefix — same buffer is
    // safe: each thread reads deg[i] before overwriting (chunk-local serial).
    fill_kernel<<<2048, 256, 0, stream>>>(adj_row, adj_col, adj_vals, cursor, csr);
    assign_kernel<<<(2 * BATCH + 255) / 256, 256, 0, stream>>>(users, items, remap, list, counter);

    // e0 = concat(user_w, item_w)
    hipMemcpyAsync(eA, user_w, (size_t)N_USERS * F * sizeof(float),
                   hipMemcpyDeviceToDevice, stream);
    hipMemcpyAsync(eA + (size_t)N_USERS * F, item_w, (size_t)N_ITEMS * F * sizeof(float),
                   hipMemcpyDeviceToDevice, stream);

    const int rows_blocks = (N_TOTAL + 3) / 4;   // 4 rows (waves) per block
    // L1: e1 = A @ e0
    spmm_layer <<<rows_blocks, 256, 0, stream>>>(row_ptr, csr, eA, eB);
    // L2: e2 = A @ e1 (into eA), fused accC = e0 + e1 at queried rows
    spmm_layer2<<<rows_blocks, 256, 0, stream>>>(row_ptr, csr, eB, eA,
                                                 user_w, item_w, remap, accC);
    // L3: queried rows only; accC += e2 + A @ e2
    spmm_layer3<<<(2 * BATCH + 3) / 4, 256, 0, stream>>>(row_ptr, csr, eA, list, counter, accC);

    batch_dot<<<(BATCH + 3) / 4, 256, 0, stream>>>(accC, remap, users, items, out);
}

// Round 13
// 940.560 us; speedup vs baseline: 3.5193x; 1.3419x over previous
//
#include <hip/hip_runtime.h>

#define N_USERS 100000
#define N_ITEMS 50000
#define N_TOTAL 150000
#define F 64
#define NNZ 4800000
#define BATCH 16384
#define SCAN_CHUNK 1024
#define SCAN_BLOCKS ((N_TOTAL + SCAN_CHUNK - 1) / SCAN_CHUNK)   // 147

// ---------------- CSR build ----------------

__global__ __launch_bounds__(256) void hist_kernel(
    const int* __restrict__ row, int* __restrict__ deg)
{
    int i = blockIdx.x * 256 + threadIdx.x;
    const int stride = gridDim.x * 256;
    for (; i < NNZ; i += stride) atomicAdd(&deg[row[i]], 1);
}

// Parallel scan, phase A: per-chunk sums. 147 blocks x 256 threads.
__global__ __launch_bounds__(256) void scanA(
    const int* __restrict__ deg, int* __restrict__ blockSum)
{
    __shared__ int red[256];
    const int b = blockIdx.x, t = threadIdx.x;
    const int base = b * SCAN_CHUNK;
    int s = 0;
    #pragma unroll
    for (int k = 0; k < 4; ++k) {
        const int i = base + t + k * 256;      // coalesced
        if (i < N_TOTAL) s += deg[i];
    }
    red[t] = s;
    __syncthreads();
    for (int off = 128; off > 0; off >>= 1) {
        if (t < off) red[t] += red[t + off];
        __syncthreads();
    }
    if (t == 0) blockSum[b] = red[0];
}

// Phase B: exclusive scan of the 147 block sums, in place. One tiny block.
__global__ __launch_bounds__(256) void scanB(int* __restrict__ blockSum)
{
    __shared__ int sh[256];
    const int t = threadIdx.x;
    const int v = (t < SCAN_BLOCKS) ? blockSum[t] : 0;
    sh[t] = v;
    __syncthreads();
    for (int off = 1; off < 256; off <<= 1) {
        const int u = (t >= off) ? sh[t - off] : 0;
        __syncthreads();
        sh[t] += u;
        __syncthreads();
    }
    if (t < SCAN_BLOCKS) blockSum[t] = sh[t] - v;   // exclusive
}

// Phase C: per-chunk local exclusive scan + chunk offset -> row_ptr, cursor.
// Each thread owns 4 CONSECUTIVE elements.
__global__ __launch_bounds__(256) void scanC(
    const int* __restrict__ deg, const int* __restrict__ blockOff,
    int* __restrict__ row_ptr, int* __restrict__ cursor)
{
    __shared__ int sh[256];
    const int b = blockIdx.x, t = threadIdx.x;
    const int lo = b * SCAN_CHUNK + t * 4;
    int d0 = 0, d1 = 0, d2 = 0, d3 = 0;
    if (lo + 0 < N_TOTAL) d0 = deg[lo + 0];
    if (lo + 1 < N_TOTAL) d1 = deg[lo + 1];
    if (lo + 2 < N_TOTAL) d2 = deg[lo + 2];
    if (lo + 3 < N_TOTAL) d3 = deg[lo + 3];
    const int s = d0 + d1 + d2 + d3;
    sh[t] = s;
    __syncthreads();
    for (int off = 1; off < 256; off <<= 1) {
        const int u = (t >= off) ? sh[t - off] : 0;
        __syncthreads();
        sh[t] += u;
        __syncthreads();
    }
    int p = blockOff[b] + sh[t] - s;   // exclusive prefix for this thread's 4
    if (lo + 0 < N_TOTAL) { row_ptr[lo + 0] = p; cursor[lo + 0] = p; p += d0; }
    if (lo + 1 < N_TOTAL) { row_ptr[lo + 1] = p; cursor[lo + 1] = p; p += d1; }
    if (lo + 2 < N_TOTAL) { row_ptr[lo + 2] = p; cursor[lo + 2] = p; p += d2; }
    if (lo + 3 < N_TOTAL) { row_ptr[lo + 3] = p; cursor[lo + 3] = p; p += d3; }
    if (b == 0 && t == 0) row_ptr[N_TOTAL] = NNZ;
}

// Bucket edges into CSR order: csr[p] = {col, bits(val)}
__global__ __launch_bounds__(256) void fill_kernel(
    const int* __restrict__ row, const int* __restrict__ col,
    const float* __restrict__ vals, int* __restrict__ cursor,
    int2* __restrict__ csr)
{
    int i = blockIdx.x * 256 + threadIdx.x;
    const int stride = gridDim.x * 256;
    for (; i < NNZ; i += stride) {
        const int r = row[i];
        const int p = atomicAdd(&cursor[r], 1);
        csr[p] = make_int2(col[i], __float_as_int(vals[i]));
    }
}

// Assign compact indices to the (deduped) queried rows.
__global__ __launch_bounds__(256) void assign_kernel(
    const int* __restrict__ users, const int* __restrict__ items,
    int* __restrict__ remap, int* __restrict__ list, int* __restrict__ counter)
{
    const int i = blockIdx.x * 256 + threadIdx.x;
    if (i >= 2 * BATCH) return;
    const int r = (i < BATCH) ? users[i] : (N_USERS + items[i - BATCH]);
    if (atomicCAS(&remap[r], -1, -2) == -1) {
        const int idx = atomicAdd(counter, 1);
        list[idx] = r;
        remap[r]  = idx;   // nobody reads remap until later kernels
    }
}

// ---------------- pull-style SpMM ----------------

// One wave computes one row: p[lane] = sum_e val_e * src[col_e][lane].
// Edge list loaded wave-wide (zero-padded), then broadcast via readlane
// (SGPR path, NO ds_bpermute) in statically-unrolled chunks of 16 so the
// 16 gathers issue back-to-back and pipeline across chunks.
// Pad lanes have v=0 -> fma contributes 0; c=0 gather hits a hot line.
__device__ __forceinline__ float spmm_row(
    const int2* __restrict__ csr, int start, int end,
    const float* __restrict__ src, int lane)
{
    float p = 0.f;
    for (int base = start; base < end; base += 64) {
        int2 cv = make_int2(0, 0);
        if (base + lane < end) cv = csr[base + lane];
        const int cnt = min(64, end - base);
        for (int ch = 0; ch < cnt; ch += 16) {
            #pragma unroll
            for (int j = 0; j < 16; ++j) {
                const int   c = __builtin_amdgcn_readlane(cv.x, ch + j);
                const float v = __int_as_float(__builtin_amdgcn_readlane(cv.y, ch + j));
                p = fmaf(v, src[(size_t)c * F + lane], p);
            }
        }
    }
    return p;
}

__global__ __launch_bounds__(256) void spmm_layer(
    const int* __restrict__ row_ptr, const int2* __restrict__ csr,
    const float* __restrict__ src, float* __restrict__ dst)
{
    const int r    = blockIdx.x * 4 + (threadIdx.x >> 6);
    const int lane = threadIdx.x & 63;
    if (r >= N_TOTAL) return;
    const float p = spmm_row(csr, row_ptr[r], row_ptr[r + 1], src, lane);
    dst[(size_t)r * F + lane] = p;
}

// Layer 2 + fused epilogue: accC[remap[r]] = e0[r] + e1[r] for queried rows.
__global__ __launch_bounds__(256) void spmm_layer2(
    const int* __restrict__ row_ptr, const int2* __restrict__ csr,
    const float* __restrict__ src /*e1*/, float* __restrict__ dst /*e2*/,
    const float* __restrict__ uw, const float* __restrict__ iw,
    const int* __restrict__ remap, float* __restrict__ accC)
{
    const int r    = blockIdx.x * 4 + (threadIdx.x >> 6);
    const int lane = threadIdx.x & 63;
    if (r >= N_TOTAL) return;
    const float p = spmm_row(csr, row_ptr[r], row_ptr[r + 1], src, lane);
    dst[(size_t)r * F + lane] = p;
    const int idx = remap[r];
    if (idx >= 0) {
        const float e0 = (r < N_USERS) ? uw[(size_t)r * F + lane]
                                       : iw[(size_t)(r - N_USERS) * F + lane];
        accC[(size_t)idx * F + lane] = e0 + src[(size_t)r * F + lane];
    }
}

// Layer 3: ONLY queried rows. accC[idx] += e2[r] + spmm_row(e2).
__global__ __launch_bounds__(256) void spmm_layer3(
    const int* __restrict__ row_ptr, const int2* __restrict__ csr,
    const float* __restrict__ src /*e2*/, const int* __restrict__ list,
    const int* __restrict__ counter, float* __restrict__ accC)
{
    const int idx  = blockIdx.x * 4 + (threadIdx.x >> 6);
    const int lane = threadIdx.x & 63;
    if (idx >= *counter) return;
    const int r = list[idx];
    const float p = spmm_row(csr, row_ptr[r], row_ptr[r + 1], src, lane);
    accC[(size_t)idx * F + lane] += src[(size_t)r * F + lane] + p;
}

// out[b] = dot(acc[u], acc[i]) / 16   (each side's /4 folded together)
__global__ __launch_bounds__(256) void batch_dot(
    const float* __restrict__ accC, const int* __restrict__ remap,
    const int* __restrict__ users, const int* __restrict__ items,
    float* __restrict__ out)
{
    const int b    = blockIdx.x * 4 + (threadIdx.x >> 6);
    const int lane = threadIdx.x & 63;
    if (b >= BATCH) return;
    const int iu = remap[users[b]];
    const int ii = remap[N_USERS + items[b]];
    float p = accC[(size_t)iu * F + lane] * accC[(size_t)ii * F + lane];
    #pragma unroll
    for (int off = 32; off > 0; off >>= 1) p += __shfl_down(p, off, 64);
    if (lane == 0) out[b] = p * (1.0f / 16.0f);
}

// ---------------- launch ----------------

extern "C" void kernel_launch(void* const* d_in, const int* in_sizes, int n_in,
                              void* d_out, int out_size, void* d_ws, size_t ws_size,
                              hipStream_t stream)
{
    const float* user_w   = (const float*)d_in[0];
    const float* item_w   = (const float*)d_in[1];
    const float* adj_vals = (const float*)d_in[2];
    const int*   adj_row  = (const int*)d_in[3];
    const int*   adj_col  = (const int*)d_in[4];
    const int*   users    = (const int*)d_in[5];
    const int*   items    = (const int*)d_in[6];
    float*       out      = (float*)d_out;

    const size_t embB  = (size_t)N_TOTAL * F * sizeof(float);   // 38.4 MB
    const size_t csrB  = (size_t)NNZ * sizeof(int2);            // 38.4 MB
    const size_t rpB   = ((size_t)(N_TOTAL + 1) * 4 + 255) & ~(size_t)255;
    const size_t curB  = ((size_t)N_TOTAL * 4 + 255) & ~(size_t)255;
    const size_t rmB   = curB;
    const size_t listB = (size_t)2 * BATCH * 4;                 // 128 KB
    const size_t cntB  = 256;
    const size_t bsB   = ((size_t)SCAN_BLOCKS * 4 + 255) & ~(size_t)255;
    const size_t accB  = (size_t)2 * BATCH * F * sizeof(float); // 8 MB

    const size_t need = 2 * embB + csrB + rpB + curB + rmB + listB + cntB + bsB + accB;
    if (ws_size < need) {   // defensive: fail visibly, never write OOB
        hipMemsetAsync(d_out, 0, (size_t)out_size * sizeof(float), stream);
        return;
    }

    char* w = (char*)d_ws;
    float* eA       = (float*)w;  w += embB;   // e0 then e2
    float* eB       = (float*)w;  w += embB;   // e1
    int2*  csr      = (int2*)w;   w += csrB;
    int*   row_ptr  = (int*)w;    w += rpB;
    int*   cursor   = (int*)w;    w += curB;   // deg, then fill cursor
    int*   remap    = (int*)w;    w += rmB;
    int*   list     = (int*)w;    w += listB;
    int*   counter  = (int*)w;    w += cntB;
    int*   blockSum = (int*)w;    w += bsB;
    float* accC     = (float*)w;  w += accB;

    // init (ws is poisoned 0xAA before every call)
    hipMemsetAsync(cursor, 0, curB, stream);
    hipMemsetAsync(remap, 0xFF, rmB, stream);          // -1
    hipMemsetAsync(counter, 0, 4, stream);

    // CSR build: hist -> 3-phase parallel scan -> fill
    hist_kernel<<<2048, 256, 0, stream>>>(adj_row, cursor);
    scanA<<<SCAN_BLOCKS, 256, 0, stream>>>(cursor, blockSum);
    scanB<<<1, 256, 0, stream>>>(blockSum);
    scanC<<<SCAN_BLOCKS, 256, 0, stream>>>(cursor, blockSum, row_ptr, cursor);
    // scanC writes cursor[i] AFTER reading deg from the same buffer: each
    // thread reads its 4 deg values into registers before any writes.
    fill_kernel<<<2048, 256, 0, stream>>>(adj_row, adj_col, adj_vals, cursor, csr);
    assign_kernel<<<(2 * BATCH + 255) / 256, 256, 0, stream>>>(users, items, remap, list, counter);

    // e0 = concat(user_w, item_w)
    hipMemcpyAsync(eA, user_w, (size_t)N_USERS * F * sizeof(float),
                   hipMemcpyDeviceToDevice, stream);
    hipMemcpyAsync(eA + (size_t)N_USERS * F, item_w, (size_t)N_ITEMS * F * sizeof(float),
                   hipMemcpyDeviceToDevice, stream);

    const int rows_blocks = (N_TOTAL + 3) / 4;   // 4 rows (waves) per block
    // L1: e1 = A @ e0
    spmm_layer <<<rows_blocks, 256, 0, stream>>>(row_ptr, csr, eA, eB);
    // L2: e2 = A @ e1 (into eA), fused accC = e0 + e1 at queried rows
    spmm_layer2<<<rows_blocks, 256, 0, stream>>>(row_ptr, csr, eB, eA,
                                                 user_w, item_w, remap, accC);
    // L3: queried rows only; accC += e2 + A @ e2
    spmm_layer3<<<(2 * BATCH + 3) / 4, 256, 0, stream>>>(row_ptr, csr, eA, list, counter, accC);

    batch_dot<<<(BATCH + 3) / 4, 256, 0, stream>>>(accC, remap, users, items, out);
}